// Round 3
// baseline (258.259 us; speedup 1.0000x reference)
//
#include <hip/hip_runtime.h>
#include <cstdint>

#define D_EDGES 64
#define K_KEEP  32

typedef unsigned long long ull;
typedef int v4i __attribute__((ext_vector_type(4)));

// Bit-exact replication of numpy's SIMD f32 exp (Cephes-based, max ULP 2.52).
// Verified: absmax 0 vs the np reference in a previous round.
__device__ __forceinline__ float np_expf(float x) {
    const float log2e     = 1.44269504088896341f;
    const float cvt_magic = 12582912.0f;            // 1.5 * 2^23 RNE trick
    const float neg_ln2hi = -0.693359375f;
    const float neg_ln2lo = 2.12194440e-4f;
    const float p0 = 1.9875691500E-4f;
    const float p1 = 1.3981999507E-3f;
    const float p2 = 8.3334519073E-3f;
    const float p3 = 4.1665795894E-2f;
    const float p4 = 1.6666665459E-1f;
    const float p5 = 5.0000001201E-1f;

    float q = fmaf(x, log2e, cvt_magic);
    q -= cvt_magic;
    x = fmaf(q, neg_ln2hi, x);
    x = fmaf(q, neg_ln2lo, x);
    float x2 = x * x;
    float poly = fmaf(p0, x, p1);
    poly = fmaf(poly, x, p2);
    poly = fmaf(poly, x, p3);
    poly = fmaf(poly, x, p4);
    poly = fmaf(poly, x, p5);
    poly = fmaf(poly, x2, x);
    poly = poly + 1.0f;
    return ldexpf(poly, (int)q);
}

__device__ __forceinline__ float sigmoid_np(float x) {
    float e = np_expf(-x);
    return 1.0f / (1.0f + e);
}

__global__ void sigmoid_kernel(const float* __restrict__ logits,
                               float* __restrict__ s, int n) {
    int i = blockIdx.x * blockDim.x + threadIdx.x;
    if (i < n) s[i] = sigmoid_np(logits[i]);
}

// Agent-scope relaxed load: bypasses the per-CU L1 (1MB table can't hit a 32KB
// L1; the L1 miss path was the round-2 wall — this bought 25%).
__device__ __forceinline__ float gather_agent(const float* p) {
    return __hip_atomic_load(p, __ATOMIC_RELAXED, __HIP_MEMORY_SCOPE_AGENT);
}

// ---- xor-shuffles of a u64 at lane distances 1,2,4 (all within 8-lane groups)
template <int CTRL>
__device__ __forceinline__ ull xor_dpp_u64(ull v) {
    int lo = (int)(unsigned)v;
    int hi = (int)(v >> 32);
    lo = __builtin_amdgcn_update_dpp(lo, lo, CTRL, 0xF, 0xF, true);
    hi = __builtin_amdgcn_update_dpp(hi, hi, CTRL, 0xF, 0xF, true);
    return ((ull)(unsigned)hi << 32) | (unsigned)lo;
}

__device__ __forceinline__ ull xor4_swz_u64(ull v) {
    int lo = (int)(unsigned)v;
    int hi = (int)(v >> 32);
    lo = __builtin_amdgcn_ds_swizzle(lo, 0x101F);   // xor4 (BitMode)
    hi = __builtin_amdgcn_ds_swizzle(hi, 0x101F);
    return ((ull)(unsigned)hi << 32) | (unsigned)lo;
}

template <int DIST>
__device__ __forceinline__ ull lane_xor_u64(ull v) {
    if constexpr (DIST == 1)      return xor_dpp_u64<0xB1>(v);   // quad_perm [1,0,3,2]
    else if constexpr (DIST == 2) return xor_dpp_u64<0x4E>(v);   // quad_perm [2,3,0,1]
    else                          return xor4_swz_u64(v);        // ds_swizzle xor4
}

// ---- 64-element bitonic sort, 8 elements per lane (elem e = 8*t + slot) ----
// Same verified network with lane -> e substituted: up = (e&K)==0,
// isLower = (e&J)==0, descending overall.

// In-lane comparator; E0 = slot of the lower element. up constant-folds for
// K<=8 (t-invariant) and K=64 (always up).
template <int K, int E0>
__device__ __forceinline__ void lce8(ull& ka, ull& kb, int t) {
    bool up = (((8 * t + E0) & K) == 0);
    bool mf = ka > kb;
    if (mf != up) { ull tmp = ka; ka = kb; kb = tmp; }
}

// Cross-lane comparator, elem distance J in {8,16,32} -> lane dist J/8, slot S.
template <int K, int J, int S>
__device__ __forceinline__ void cce8(ull& k, int t) {
    ull other = lane_xor_u64<J / 8>(k);
    int e = 8 * t + S;
    bool up  = ((e & K) == 0);
    bool low = ((e & J) == 0);
    bool mf  = k > other;
    if (mf != (low == up)) k = other;
}

template <int K, int J>
__device__ __forceinline__ void cross8(ull& k0, ull& k1, ull& k2, ull& k3,
                                       ull& k4, ull& k5, ull& k6, ull& k7, int t) {
    cce8<K, J, 0>(k0, t); cce8<K, J, 1>(k1, t);
    cce8<K, J, 2>(k2, t); cce8<K, J, 3>(k3, t);
    cce8<K, J, 4>(k4, t); cce8<K, J, 5>(k5, t);
    cce8<K, J, 6>(k6, t); cce8<K, J, 7>(k7, t);
}

template <int K>
__device__ __forceinline__ void inlane1(ull& k0, ull& k1, ull& k2, ull& k3,
                                        ull& k4, ull& k5, ull& k6, ull& k7, int t) {
    lce8<K, 0>(k0, k1, t); lce8<K, 2>(k2, k3, t);
    lce8<K, 4>(k4, k5, t); lce8<K, 6>(k6, k7, t);
}

template <int K>
__device__ __forceinline__ void inlane2(ull& k0, ull& k1, ull& k2, ull& k3,
                                        ull& k4, ull& k5, ull& k6, ull& k7, int t) {
    lce8<K, 0>(k0, k2, t); lce8<K, 1>(k1, k3, t);
    lce8<K, 4>(k4, k6, t); lce8<K, 5>(k5, k7, t);
}

template <int K>
__device__ __forceinline__ void inlane4(ull& k0, ull& k1, ull& k2, ull& k3,
                                        ull& k4, ull& k5, ull& k6, ull& k7, int t) {
    lce8<K, 0>(k0, k4, t); lce8<K, 1>(k1, k5, t);
    lce8<K, 2>(k2, k6, t); lce8<K, 3>(k3, k7, t);
}

// Key layout (54 significant bits):
//   [63:34] simbits  [33:28] e^63 (tie -> lower index)  [27:0] src payload
__device__ __forceinline__ ull make_key(float sim, int e, int src) {
    unsigned sb  = __float_as_uint(sim);
    unsigned e63 = (unsigned)(e ^ 63);
    unsigned hi  = (sb << 2) | (e63 >> 4);
    unsigned lo  = (e63 << 28) | (unsigned)src;
    return ((ull)hi << 32) | lo;
}

// 8 segments per wave; segment = 8-lane group q = lane>>3, t = lane&7; each
// lane owns elems 8t..8t+7. After the descending sort, rank p lives at
// (t = p>>3, slot = p&7), so ranks 0..31 sit in t < 4.
// dst is constant within a segment (edges grouped by dest — problem invariant).
template <bool USE_TABLE>
__global__ void __launch_bounds__(256)
topk_kernel(const int* __restrict__ edge_index,   // [2, E]
            const float* __restrict__ s,
            const float* __restrict__ logits,
            int* __restrict__ out,                // [2, nseg*K]
            long long E, long long nseg) {
    long long gtid = (long long)blockIdx.x * blockDim.x + threadIdx.x;
    long long w = gtid >> 6;
    int lane = (int)(gtid & 63);
    int q = lane >> 3;
    int t = lane & 7;
    long long g = w * 8 + q;                 // segment id (8-lane-group uniform)
    if (g >= nseg) return;

    const int* ebase = edge_index + g * D_EDGES + 8 * t;
    v4i sva = __builtin_nontemporal_load(reinterpret_cast<const v4i*>(ebase));
    v4i svb = __builtin_nontemporal_load(reinterpret_cast<const v4i*>(ebase + 4));
    int dstv = edge_index[E + g * D_EDGES];  // one word per segment (broadcast)

    float sd, ss0, ss1, ss2, ss3, ss4, ss5, ss6, ss7;
    if constexpr (USE_TABLE) {
        sd  = s[dstv];
        ss0 = gather_agent(s + sva.x); ss1 = gather_agent(s + sva.y);
        ss2 = gather_agent(s + sva.z); ss3 = gather_agent(s + sva.w);
        ss4 = gather_agent(s + svb.x); ss5 = gather_agent(s + svb.y);
        ss6 = gather_agent(s + svb.z); ss7 = gather_agent(s + svb.w);
    } else {
        sd  = sigmoid_np(logits[dstv]);
        ss0 = sigmoid_np(gather_agent(logits + sva.x));
        ss1 = sigmoid_np(gather_agent(logits + sva.y));
        ss2 = sigmoid_np(gather_agent(logits + sva.z));
        ss3 = sigmoid_np(gather_agent(logits + sva.w));
        ss4 = sigmoid_np(gather_agent(logits + svb.x));
        ss5 = sigmoid_np(gather_agent(logits + svb.y));
        ss6 = sigmoid_np(gather_agent(logits + svb.z));
        ss7 = sigmoid_np(gather_agent(logits + svb.w));
    }

    ull k0 = make_key(1.0f - fabsf(ss0 - sd), 8 * t + 0, sva.x);
    ull k1 = make_key(1.0f - fabsf(ss1 - sd), 8 * t + 1, sva.y);
    ull k2 = make_key(1.0f - fabsf(ss2 - sd), 8 * t + 2, sva.z);
    ull k3 = make_key(1.0f - fabsf(ss3 - sd), 8 * t + 3, sva.w);
    ull k4 = make_key(1.0f - fabsf(ss4 - sd), 8 * t + 4, svb.x);
    ull k5 = make_key(1.0f - fabsf(ss5 - sd), 8 * t + 5, svb.y);
    ull k6 = make_key(1.0f - fabsf(ss6 - sd), 8 * t + 6, svb.z);
    ull k7 = make_key(1.0f - fabsf(ss7 - sd), 8 * t + 7, svb.w);

    // 21 substages; 15 in-lane (no shuffle), 4 quad_perm DPP, 2 ds_swizzle.
    inlane1<2>(k0,k1,k2,k3,k4,k5,k6,k7,t);
    inlane2<4>(k0,k1,k2,k3,k4,k5,k6,k7,t);   inlane1<4>(k0,k1,k2,k3,k4,k5,k6,k7,t);
    inlane4<8>(k0,k1,k2,k3,k4,k5,k6,k7,t);
    inlane2<8>(k0,k1,k2,k3,k4,k5,k6,k7,t);   inlane1<8>(k0,k1,k2,k3,k4,k5,k6,k7,t);
    cross8<16, 8>(k0,k1,k2,k3,k4,k5,k6,k7,t);
    inlane4<16>(k0,k1,k2,k3,k4,k5,k6,k7,t);
    inlane2<16>(k0,k1,k2,k3,k4,k5,k6,k7,t);  inlane1<16>(k0,k1,k2,k3,k4,k5,k6,k7,t);
    cross8<32, 16>(k0,k1,k2,k3,k4,k5,k6,k7,t);
    cross8<32, 8>(k0,k1,k2,k3,k4,k5,k6,k7,t);
    inlane4<32>(k0,k1,k2,k3,k4,k5,k6,k7,t);
    inlane2<32>(k0,k1,k2,k3,k4,k5,k6,k7,t);  inlane1<32>(k0,k1,k2,k3,k4,k5,k6,k7,t);
    cross8<64, 32>(k0,k1,k2,k3,k4,k5,k6,k7,t);
    cross8<64, 16>(k0,k1,k2,k3,k4,k5,k6,k7,t);
    cross8<64, 8>(k0,k1,k2,k3,k4,k5,k6,k7,t);
    inlane4<64>(k0,k1,k2,k3,k4,k5,k6,k7,t);
    inlane2<64>(k0,k1,k2,k3,k4,k5,k6,k7,t);  inlane1<64>(k0,k1,k2,k3,k4,k5,k6,k7,t);

    if (t < 4) {
        long long base = g * K_KEEP + 8 * t;
        v4i ra, rb, dv;
        ra.x = (int)(k0 & 0x0FFFFFFFu); ra.y = (int)(k1 & 0x0FFFFFFFu);
        ra.z = (int)(k2 & 0x0FFFFFFFu); ra.w = (int)(k3 & 0x0FFFFFFFu);
        rb.x = (int)(k4 & 0x0FFFFFFFu); rb.y = (int)(k5 & 0x0FFFFFFFu);
        rb.z = (int)(k6 & 0x0FFFFFFFu); rb.w = (int)(k7 & 0x0FFFFFFFu);
        dv.x = dstv; dv.y = dstv; dv.z = dstv; dv.w = dstv;
        int* o0 = out + base;
        int* o1 = out + nseg * K_KEEP + base;
        __builtin_nontemporal_store(ra, reinterpret_cast<v4i*>(o0));
        __builtin_nontemporal_store(rb, reinterpret_cast<v4i*>(o0 + 4));
        __builtin_nontemporal_store(dv, reinterpret_cast<v4i*>(o1));
        __builtin_nontemporal_store(dv, reinterpret_cast<v4i*>(o1 + 4));
    }
}

extern "C" void kernel_launch(void* const* d_in, const int* in_sizes, int n_in,
                              void* d_out, int out_size, void* d_ws, size_t ws_size,
                              hipStream_t stream) {
    const float* logits = (const float*)d_in[0];
    const int* edge_index = (const int*)d_in[1];
    int N = in_sizes[0];
    long long E = (long long)in_sizes[1] / 2;
    long long nseg = E / D_EDGES;
    int* out = (int*)d_out;

    long long nwave = (nseg + 7) / 8;            // 8 segments per wave
    long long total_threads = nwave * 64;
    int blocks = (int)((total_threads + 255) / 256);

    if (ws_size >= (size_t)N * sizeof(float)) {
        float* s = (float*)d_ws;
        sigmoid_kernel<<<(N + 255) / 256, 256, 0, stream>>>(logits, s, N);
        topk_kernel<true><<<blocks, 256, 0, stream>>>(edge_index, s, logits, out, E, nseg);
    } else {
        topk_kernel<false><<<blocks, 256, 0, stream>>>(edge_index, nullptr, logits, out, E, nseg);
    }
}

// Round 4
// 257.638 us; speedup vs baseline: 1.0024x; 1.0024x over previous
//
#include <hip/hip_runtime.h>
#include <cstdint>

#define D_EDGES 64
#define K_KEEP  32

typedef unsigned long long ull;
typedef int v4i __attribute__((ext_vector_type(4)));

// Bit-exact replication of numpy's SIMD f32 exp (Cephes-based, max ULP 2.52).
// Verified: absmax 0 vs the np reference in a previous round.
__device__ __forceinline__ float np_expf(float x) {
    const float log2e     = 1.44269504088896341f;
    const float cvt_magic = 12582912.0f;            // 1.5 * 2^23 RNE trick
    const float neg_ln2hi = -0.693359375f;
    const float neg_ln2lo = 2.12194440e-4f;
    const float p0 = 1.9875691500E-4f;
    const float p1 = 1.3981999507E-3f;
    const float p2 = 8.3334519073E-3f;
    const float p3 = 4.1665795894E-2f;
    const float p4 = 1.6666665459E-1f;
    const float p5 = 5.0000001201E-1f;

    float q = fmaf(x, log2e, cvt_magic);
    q -= cvt_magic;
    x = fmaf(q, neg_ln2hi, x);
    x = fmaf(q, neg_ln2lo, x);
    float x2 = x * x;
    float poly = fmaf(p0, x, p1);
    poly = fmaf(poly, x, p2);
    poly = fmaf(poly, x, p3);
    poly = fmaf(poly, x, p4);
    poly = fmaf(poly, x, p5);
    poly = fmaf(poly, x2, x);
    poly = poly + 1.0f;
    return ldexpf(poly, (int)q);
}

__device__ __forceinline__ float sigmoid_np(float x) {
    float e = np_expf(-x);
    return 1.0f / (1.0f + e);
}

__global__ void sigmoid_kernel(const float* __restrict__ logits,
                               float* __restrict__ s, int n) {
    int i = blockIdx.x * blockDim.x + threadIdx.x;
    if (i < n) s[i] = sigmoid_np(logits[i]);
}

// Agent-scope relaxed load: bypasses the per-CU L1 (1MB table can't hit a 32KB
// L1; the L1 miss path was the round-2 wall — this bought 25%).
__device__ __forceinline__ float gather_agent(const float* p) {
    return __hip_atomic_load(p, __ATOMIC_RELAXED, __HIP_MEMORY_SCOPE_AGENT);
}

// ---- xor-shuffles of a u64 at lane distances 1,2,4,8 ----
template <int CTRL>
__device__ __forceinline__ ull xor_dpp_u64(ull v) {
    int lo = (int)(unsigned)v;
    int hi = (int)(v >> 32);
    lo = __builtin_amdgcn_update_dpp(lo, lo, CTRL, 0xF, 0xF, true);
    hi = __builtin_amdgcn_update_dpp(hi, hi, CTRL, 0xF, 0xF, true);
    return ((ull)(unsigned)hi << 32) | (unsigned)lo;
}

__device__ __forceinline__ ull xor4_swz_u64(ull v) {
    int lo = (int)(unsigned)v;
    int hi = (int)(v >> 32);
    lo = __builtin_amdgcn_ds_swizzle(lo, 0x101F);   // xor4 (BitMode)
    hi = __builtin_amdgcn_ds_swizzle(hi, 0x101F);
    return ((ull)(unsigned)hi << 32) | (unsigned)lo;
}

template <int DIST>
__device__ __forceinline__ ull lane_xor_u64(ull v) {
    if constexpr (DIST == 1)      return xor_dpp_u64<0xB1>(v);   // quad_perm [1,0,3,2]
    else if constexpr (DIST == 2) return xor_dpp_u64<0x4E>(v);   // quad_perm [2,3,0,1]
    else if constexpr (DIST == 4) return xor4_swz_u64(v);        // ds_swizzle xor4
    else                          return xor_dpp_u64<0x128>(v);  // row_ror:8 == xor8
}

// ---- 64-element bitonic sort, 4 elements per lane (elem e = 4*t + slot) ----
// The round-2-verified network: up = (e&K)==0, isLower = (e&J)==0, descending.
template <int K, int S1>
__device__ __forceinline__ void lce(ull& ka, ull& kb, int t) {
    bool up = (((4 * t + S1) & K) == 0);
    bool mf = ka > kb;
    if (mf != up) { ull tmp = ka; ka = kb; kb = tmp; }
}

template <int K, int J, int S>
__device__ __forceinline__ void cce(ull& k, int t) {
    ull other = lane_xor_u64<J / 4>(k);
    int e = 4 * t + S;
    bool up  = ((e & K) == 0);
    bool low = ((e & J) == 0);
    bool mf  = k > other;
    if (mf != (low == up)) k = other;
}

template <int K, int J>
__device__ __forceinline__ void cce4(ull& k0, ull& k1, ull& k2, ull& k3, int t) {
    cce<K, J, 0>(k0, t);
    cce<K, J, 1>(k1, t);
    cce<K, J, 2>(k2, t);
    cce<K, J, 3>(k3, t);
}

template <int K>
__device__ __forceinline__ void lceJ1(ull& k0, ull& k1, ull& k2, ull& k3, int t) {
    lce<K, 0>(k0, k1, t);
    lce<K, 2>(k2, k3, t);
}

template <int K>
__device__ __forceinline__ void lceJ2(ull& k0, ull& k1, ull& k2, ull& k3, int t) {
    lce<K, 0>(k0, k2, t);
    lce<K, 1>(k1, k3, t);
}

// Full 64-elem sort, 21 substages (10 in-lane, 8 quad/ror DPP, 2 ds_swizzle).
__device__ __forceinline__ void sort64(ull& k0, ull& k1, ull& k2, ull& k3, int t) {
    lceJ1<2>(k0, k1, k2, k3, t);
    lceJ2<4>(k0, k1, k2, k3, t);   lceJ1<4>(k0, k1, k2, k3, t);
    cce4<8, 4>(k0, k1, k2, k3, t);
    lceJ2<8>(k0, k1, k2, k3, t);   lceJ1<8>(k0, k1, k2, k3, t);
    cce4<16, 8>(k0, k1, k2, k3, t);
    cce4<16, 4>(k0, k1, k2, k3, t);
    lceJ2<16>(k0, k1, k2, k3, t);  lceJ1<16>(k0, k1, k2, k3, t);
    cce4<32, 16>(k0, k1, k2, k3, t);
    cce4<32, 8>(k0, k1, k2, k3, t);
    cce4<32, 4>(k0, k1, k2, k3, t);
    lceJ2<32>(k0, k1, k2, k3, t);  lceJ1<32>(k0, k1, k2, k3, t);
    cce4<64, 32>(k0, k1, k2, k3, t);
    cce4<64, 16>(k0, k1, k2, k3, t);
    cce4<64, 8>(k0, k1, k2, k3, t);
    cce4<64, 4>(k0, k1, k2, k3, t);
    lceJ2<64>(k0, k1, k2, k3, t);  lceJ1<64>(k0, k1, k2, k3, t);
}

// Key layout (54 significant bits):
//   [63:34] simbits  [33:28] e^63 (tie -> lower index)  [27:0] src payload
__device__ __forceinline__ ull make_key(float sim, int e, int src) {
    unsigned sb  = __float_as_uint(sim);
    unsigned e63 = (unsigned)(e ^ 63);
    unsigned hi  = (sb << 2) | (e63 >> 4);
    unsigned lo  = (e63 << 28) | (unsigned)src;
    return ((ull)hi << 32) | lo;
}

__device__ __forceinline__ void store_sel(int* __restrict__ out, long long nseg,
                                          long long g, int t, int dstv,
                                          ull k0, ull k1, ull k2, ull k3) {
    long long base = g * K_KEEP + 4 * t;
    v4i r0, dv;
    r0.x = (int)(k0 & 0x0FFFFFFFu);
    r0.y = (int)(k1 & 0x0FFFFFFFu);
    r0.z = (int)(k2 & 0x0FFFFFFFu);
    r0.w = (int)(k3 & 0x0FFFFFFFu);
    dv.x = dstv; dv.y = dstv; dv.z = dstv; dv.w = dstv;
    __builtin_nontemporal_store(r0, reinterpret_cast<v4i*>(out + base));
    __builtin_nontemporal_store(dv, reinterpret_cast<v4i*>(out + nseg * K_KEEP + base));
}

// Round-2 structure (4 seg/wave, 4 elem/lane) + 2-chunk software pipeline:
// each wave owns chunks A (segments w*8+q) and B (w*8+4+q).  ALL loads are
// issued up front — edge A, edge B, gathers A, gathers B — so chunk B's
// memory latency hides under chunk A's ~640-cycle in-register sort.
template <bool USE_TABLE>
__global__ void __launch_bounds__(256)
topk_kernel(const int* __restrict__ edge_index,   // [2, E]
            const float* __restrict__ s,
            const float* __restrict__ logits,
            int* __restrict__ out,                // [2, nseg*K]
            long long E, long long nseg) {
    long long gtid = (long long)blockIdx.x * blockDim.x + threadIdx.x;
    long long w = gtid >> 6;
    int lane = (int)(gtid & 63);
    int q = lane >> 4;
    int t = lane & 15;

    long long gA = w * 8 + q;            // chunk A segment
    long long gB = w * 8 + 4 + q;        // chunk B segment
    bool vA = gA < nseg;
    bool vB = gB < nseg;
    if (!vA) return;                     // gB > gA: if A invalid, both are
    long long gBc = vB ? gB : gA;        // clamp: load valid memory, mask store

    // --- issue ALL edge loads first ---
    v4i svA = __builtin_nontemporal_load(
        reinterpret_cast<const v4i*>(edge_index + gA * D_EDGES + 4 * t));
    v4i svB = __builtin_nontemporal_load(
        reinterpret_cast<const v4i*>(edge_index + gBc * D_EDGES + 4 * t));
    int dstA = edge_index[E + gA * D_EDGES];   // 1 word/segment (group-uniform)
    int dstB = edge_index[E + gBc * D_EDGES];

    // --- issue ALL gathers (A then B) before any compute ---
    float sdA, a0, a1, a2, a3, sdB, b0, b1, b2, b3;
    if constexpr (USE_TABLE) {
        a0 = gather_agent(s + svA.x); a1 = gather_agent(s + svA.y);
        a2 = gather_agent(s + svA.z); a3 = gather_agent(s + svA.w);
        b0 = gather_agent(s + svB.x); b1 = gather_agent(s + svB.y);
        b2 = gather_agent(s + svB.z); b3 = gather_agent(s + svB.w);
        sdA = s[dstA];
        sdB = s[dstB];
    } else {
        a0 = sigmoid_np(gather_agent(logits + svA.x));
        a1 = sigmoid_np(gather_agent(logits + svA.y));
        a2 = sigmoid_np(gather_agent(logits + svA.z));
        a3 = sigmoid_np(gather_agent(logits + svA.w));
        b0 = sigmoid_np(gather_agent(logits + svB.x));
        b1 = sigmoid_np(gather_agent(logits + svB.y));
        b2 = sigmoid_np(gather_agent(logits + svB.z));
        b3 = sigmoid_np(gather_agent(logits + svB.w));
        sdA = sigmoid_np(logits[dstA]);
        sdB = sigmoid_np(logits[dstB]);
    }

    // --- chunk A: keys, sort, store (B's gathers still in flight) ---
    ull kA0 = make_key(1.0f - fabsf(a0 - sdA), 4 * t + 0, svA.x);
    ull kA1 = make_key(1.0f - fabsf(a1 - sdA), 4 * t + 1, svA.y);
    ull kA2 = make_key(1.0f - fabsf(a2 - sdA), 4 * t + 2, svA.z);
    ull kA3 = make_key(1.0f - fabsf(a3 - sdA), 4 * t + 3, svA.w);
    sort64(kA0, kA1, kA2, kA3, t);
    if (t < 8) store_sel(out, nseg, gA, t, dstA, kA0, kA1, kA2, kA3);

    // --- chunk B ---
    if (!vB) return;
    ull kB0 = make_key(1.0f - fabsf(b0 - sdB), 4 * t + 0, svB.x);
    ull kB1 = make_key(1.0f - fabsf(b1 - sdB), 4 * t + 1, svB.y);
    ull kB2 = make_key(1.0f - fabsf(b2 - sdB), 4 * t + 2, svB.z);
    ull kB3 = make_key(1.0f - fabsf(b3 - sdB), 4 * t + 3, svB.w);
    sort64(kB0, kB1, kB2, kB3, t);
    if (t < 8) store_sel(out, nseg, gB, t, dstB, kB0, kB1, kB2, kB3);
}

extern "C" void kernel_launch(void* const* d_in, const int* in_sizes, int n_in,
                              void* d_out, int out_size, void* d_ws, size_t ws_size,
                              hipStream_t stream) {
    const float* logits = (const float*)d_in[0];
    const int* edge_index = (const int*)d_in[1];
    int N = in_sizes[0];
    long long E = (long long)in_sizes[1] / 2;
    long long nseg = E / D_EDGES;
    int* out = (int*)d_out;

    long long nwave = (nseg + 7) / 8;            // 2 chunks x 4 segments per wave
    long long total_threads = nwave * 64;
    int blocks = (int)((total_threads + 255) / 256);

    if (ws_size >= (size_t)N * sizeof(float)) {
        float* s = (float*)d_ws;
        sigmoid_kernel<<<(N + 255) / 256, 256, 0, stream>>>(logits, s, N);
        topk_kernel<true><<<blocks, 256, 0, stream>>>(edge_index, s, logits, out, E, nseg);
    } else {
        topk_kernel<false><<<blocks, 256, 0, stream>>>(edge_index, nullptr, logits, out, E, nseg);
    }
}

// Round 5
// 250.673 us; speedup vs baseline: 1.0303x; 1.0278x over previous
//
#include <hip/hip_runtime.h>
#include <cstdint>

#define D_EDGES 64
#define K_KEEP  32

typedef unsigned long long ull;
typedef int v4i __attribute__((ext_vector_type(4)));

// Bit-exact replication of numpy's SIMD f32 exp (Cephes-based, max ULP 2.52).
// Verified: absmax 0 vs the np reference in a previous round.
__device__ __forceinline__ float np_expf(float x) {
    const float log2e     = 1.44269504088896341f;
    const float cvt_magic = 12582912.0f;            // 1.5 * 2^23 RNE trick
    const float neg_ln2hi = -0.693359375f;
    const float neg_ln2lo = 2.12194440e-4f;
    const float p0 = 1.9875691500E-4f;
    const float p1 = 1.3981999507E-3f;
    const float p2 = 8.3334519073E-3f;
    const float p3 = 4.1665795894E-2f;
    const float p4 = 1.6666665459E-1f;
    const float p5 = 5.0000001201E-1f;

    float q = fmaf(x, log2e, cvt_magic);
    q -= cvt_magic;
    x = fmaf(q, neg_ln2hi, x);
    x = fmaf(q, neg_ln2lo, x);
    float x2 = x * x;
    float poly = fmaf(p0, x, p1);
    poly = fmaf(poly, x, p2);
    poly = fmaf(poly, x, p3);
    poly = fmaf(poly, x, p4);
    poly = fmaf(poly, x, p5);
    poly = fmaf(poly, x2, x);
    poly = poly + 1.0f;
    return ldexpf(poly, (int)q);
}

__device__ __forceinline__ float sigmoid_np(float x) {
    float e = np_expf(-x);
    return 1.0f / (1.0f + e);
}

__global__ void sigmoid_kernel(const float* __restrict__ logits,
                               float* __restrict__ s, int n) {
    int i = blockIdx.x * blockDim.x + threadIdx.x;
    if (i < n) s[i] = sigmoid_np(logits[i]);
}

// Agent-scope relaxed load: bypasses the per-CU L1 (the 1MB table can never
// hit a 32KB L1; the L1 miss path was the round-1 wall — bypassing it bought
// 25% in round 2).
__device__ __forceinline__ float gather_agent(const float* p) {
    return __hip_atomic_load(p, __ATOMIC_RELAXED, __HIP_MEMORY_SCOPE_AGENT);
}

// ---- xor-shuffles of a u64 at lane distances 1,2,4,8 ----
template <int CTRL>
__device__ __forceinline__ ull xor_dpp_u64(ull v) {
    int lo = (int)(unsigned)v;
    int hi = (int)(v >> 32);
    lo = __builtin_amdgcn_update_dpp(lo, lo, CTRL, 0xF, 0xF, true);
    hi = __builtin_amdgcn_update_dpp(hi, hi, CTRL, 0xF, 0xF, true);
    return ((ull)(unsigned)hi << 32) | (unsigned)lo;
}

__device__ __forceinline__ ull xor4_swz_u64(ull v) {
    int lo = (int)(unsigned)v;
    int hi = (int)(v >> 32);
    lo = __builtin_amdgcn_ds_swizzle(lo, 0x101F);   // xor4 (BitMode)
    hi = __builtin_amdgcn_ds_swizzle(hi, 0x101F);
    return ((ull)(unsigned)hi << 32) | (unsigned)lo;
}

template <int DIST>
__device__ __forceinline__ ull lane_xor_u64(ull v) {
    if constexpr (DIST == 1)      return xor_dpp_u64<0xB1>(v);   // quad_perm [1,0,3,2]
    else if constexpr (DIST == 2) return xor_dpp_u64<0x4E>(v);   // quad_perm [2,3,0,1]
    else if constexpr (DIST == 4) return xor4_swz_u64(v);        // ds_swizzle xor4
    else                          return xor_dpp_u64<0x128>(v);  // row_ror:8 == xor8
}

// ---- 64-element bitonic sort, 4 elements per lane (elem e = 4*t + slot) ----
// Verified network: up = (e&K)==0, isLower = (e&J)==0, descending overall.
//
// Session record (why THIS shape):
//   1 elem/lane  = 122 µs (shuffle-heavy, no ILP)
//   4 elem/lane  =  91 µs (this kernel)          <- optimum
//   8 elem/lane  =  98 µs (fewer shuffles but halves wave-level MLP)
//   2x4 pipeline =  97 µs (same wave count as 8/lane; SW pipelining does NOT
//                          recover the loss -> latency is hidden by TLP only)
template <int K, int S1>
__device__ __forceinline__ void lce(ull& ka, ull& kb, int t) {
    bool up = (((4 * t + S1) & K) == 0);
    bool mf = ka > kb;
    if (mf != up) { ull tmp = ka; ka = kb; kb = tmp; }
}

template <int K, int J, int S>
__device__ __forceinline__ void cce(ull& k, int t) {
    ull other = lane_xor_u64<J / 4>(k);
    int e = 4 * t + S;
    bool up  = ((e & K) == 0);
    bool low = ((e & J) == 0);
    bool mf  = k > other;
    if (mf != (low == up)) k = other;
}

template <int K, int J>
__device__ __forceinline__ void cce4(ull& k0, ull& k1, ull& k2, ull& k3, int t) {
    cce<K, J, 0>(k0, t);
    cce<K, J, 1>(k1, t);
    cce<K, J, 2>(k2, t);
    cce<K, J, 3>(k3, t);
}

template <int K>
__device__ __forceinline__ void lceJ1(ull& k0, ull& k1, ull& k2, ull& k3, int t) {
    lce<K, 0>(k0, k1, t);
    lce<K, 2>(k2, k3, t);
}

template <int K>
__device__ __forceinline__ void lceJ2(ull& k0, ull& k1, ull& k2, ull& k3, int t) {
    lce<K, 0>(k0, k2, t);
    lce<K, 1>(k1, k3, t);
}

// Key layout (54 significant bits):
//   [63:34] simbits  [33:28] e^63 (tie -> lower index)  [27:0] src payload
__device__ __forceinline__ ull make_key(float sim, int e, int src) {
    unsigned sb  = __float_as_uint(sim);
    unsigned e63 = (unsigned)(e ^ 63);
    unsigned hi  = (sb << 2) | (e63 >> 4);
    unsigned lo  = (e63 << 28) | (unsigned)src;
    return ((ull)hi << 32) | lo;
}

// 4 segments per wave; segment = 16-lane group q, t = lane&15; lane owns
// elems 4t..4t+3. After descending sort, rank p is at (t=p>>2, slot=p&3).
// dst is constant within a segment (edges grouped by dest — problem invariant).
template <bool USE_TABLE>
__global__ void __launch_bounds__(256)
topk_kernel(const int* __restrict__ edge_index,   // [2, E]
            const float* __restrict__ s,
            const float* __restrict__ logits,
            int* __restrict__ out,                // [2, nseg*K]
            long long E, long long nseg) {
    long long gtid = (long long)blockIdx.x * blockDim.x + threadIdx.x;
    long long w = gtid >> 6;
    int lane = (int)(gtid & 63);
    int q = lane >> 4;
    int t = lane & 15;
    long long g = w * 4 + q;                 // segment id
    if (g >= nseg) return;

    // Streaming data: nontemporal (evict-first) so the 1MB gather table
    // keeps its L2 residency against the two 67MB streams.
    v4i sv = __builtin_nontemporal_load(
        reinterpret_cast<const v4i*>(edge_index + g * D_EDGES + 4 * t));
    int dstv = edge_index[E + g * D_EDGES];  // one word per segment (broadcast)

    float sd, ss0, ss1, ss2, ss3;
    if constexpr (USE_TABLE) {
        sd  = s[dstv];
        ss0 = gather_agent(s + sv.x);
        ss1 = gather_agent(s + sv.y);
        ss2 = gather_agent(s + sv.z);
        ss3 = gather_agent(s + sv.w);
    } else {
        sd  = sigmoid_np(logits[dstv]);
        ss0 = sigmoid_np(gather_agent(logits + sv.x));
        ss1 = sigmoid_np(gather_agent(logits + sv.y));
        ss2 = sigmoid_np(gather_agent(logits + sv.z));
        ss3 = sigmoid_np(gather_agent(logits + sv.w));
    }

    ull k0 = make_key(1.0f - fabsf(ss0 - sd), 4 * t + 0, sv.x);
    ull k1 = make_key(1.0f - fabsf(ss1 - sd), 4 * t + 1, sv.y);
    ull k2 = make_key(1.0f - fabsf(ss2 - sd), 4 * t + 2, sv.z);
    ull k3 = make_key(1.0f - fabsf(ss3 - sd), 4 * t + 3, sv.w);

    // 21 substages; 10 in-lane (no shuffle), 8 quad/ror DPP, 2 ds_swizzle.
    lceJ1<2>(k0, k1, k2, k3, t);
    lceJ2<4>(k0, k1, k2, k3, t);   lceJ1<4>(k0, k1, k2, k3, t);
    cce4<8, 4>(k0, k1, k2, k3, t);
    lceJ2<8>(k0, k1, k2, k3, t);   lceJ1<8>(k0, k1, k2, k3, t);
    cce4<16, 8>(k0, k1, k2, k3, t);
    cce4<16, 4>(k0, k1, k2, k3, t);
    lceJ2<16>(k0, k1, k2, k3, t);  lceJ1<16>(k0, k1, k2, k3, t);
    cce4<32, 16>(k0, k1, k2, k3, t);
    cce4<32, 8>(k0, k1, k2, k3, t);
    cce4<32, 4>(k0, k1, k2, k3, t);
    lceJ2<32>(k0, k1, k2, k3, t);  lceJ1<32>(k0, k1, k2, k3, t);
    cce4<64, 32>(k0, k1, k2, k3, t);
    cce4<64, 16>(k0, k1, k2, k3, t);
    cce4<64, 8>(k0, k1, k2, k3, t);
    cce4<64, 4>(k0, k1, k2, k3, t);
    lceJ2<64>(k0, k1, k2, k3, t);  lceJ1<64>(k0, k1, k2, k3, t);

    if (t < 8) {
        long long base = g * K_KEEP + 4 * t;
        v4i r0;
        r0.x = (int)(k0 & 0x0FFFFFFFu);
        r0.y = (int)(k1 & 0x0FFFFFFFu);
        r0.z = (int)(k2 & 0x0FFFFFFFu);
        r0.w = (int)(k3 & 0x0FFFFFFFu);
        v4i dv;
        dv.x = dstv; dv.y = dstv; dv.z = dstv; dv.w = dstv;
        __builtin_nontemporal_store(r0, reinterpret_cast<v4i*>(out + base));
        __builtin_nontemporal_store(dv, reinterpret_cast<v4i*>(out + nseg * K_KEEP + base));
    }
}

extern "C" void kernel_launch(void* const* d_in, const int* in_sizes, int n_in,
                              void* d_out, int out_size, void* d_ws, size_t ws_size,
                              hipStream_t stream) {
    const float* logits = (const float*)d_in[0];
    const int* edge_index = (const int*)d_in[1];
    int N = in_sizes[0];
    long long E = (long long)in_sizes[1] / 2;
    long long nseg = E / D_EDGES;
    int* out = (int*)d_out;

    long long nwave = (nseg + 3) / 4;            // 4 segments per wave
    long long total_threads = nwave * 64;
    int blocks = (int)((total_threads + 255) / 256);

    if (ws_size >= (size_t)N * sizeof(float)) {
        float* s = (float*)d_ws;
        sigmoid_kernel<<<(N + 255) / 256, 256, 0, stream>>>(logits, s, N);
        topk_kernel<true><<<blocks, 256, 0, stream>>>(edge_index, s, logits, out, E, nseg);
    } else {
        topk_kernel<false><<<blocks, 256, 0, stream>>>(edge_index, nullptr, logits, out, E, nseg);
    }
}